// Round 7
// baseline (484.798 us; speedup 1.0000x reference)
//
#include <hip/hip_runtime.h>
#include <math.h>

#define BATCH    8192
#define TSTEPS   128
#define SDIM     16
#define HID      50
#define IN0      17
#define BT       16     // samples per block = MFMA N
#define NTHREADS 256    // 4 waves

// Unified state row (f16 elems), double-buffered:
//   k 0..15  : x features        k 16     : prev_delta
//   k 17..31 : zero pad          k 32..95 : h0 (64 slots, 50 real)
//   k 96..159: h1 (64 slots, 50 real)
#define RS      160
#define OFF_H0  32
#define OFF_H1  96
#define W0K     96      // W0 row k-layout: [wx16|wd|0*15|wh0(50)|0*14]
#define W1K     128     // W1 row k-layout: [w_ih1(50)|0*14 | w_hh1(50)|0*14]
#define WFK     64      // Wf row k-layout: [w_fc1(50)|0*14]

typedef _Float16 half_t;
typedef __attribute__((ext_vector_type(8))) _Float16 half8;
typedef __attribute__((ext_vector_type(4))) float    floatx4;

#define MFMA16(a, b, c) __builtin_amdgcn_mfma_f32_16x16x32_f16((a), (b), (c), 0, 0, 0)

__device__ __forceinline__ float sig_u(float x) {
    float e = __expf(-x);
    return __builtin_amdgcn_rcpf(1.0f + e);
}
__device__ __forceinline__ float tanh_u(float x) {
    float e = __expf(-2.0f * x);
    return fmaf(2.0f, __builtin_amdgcn_rcpf(1.0f + e), -1.0f);
}
__device__ __forceinline__ void hsplit(float v, half_t* hp, half_t* lp) {
    half_t h = (half_t)v;
    *hp = h;
    *lp = (half_t)(v - (float)h);
}

__global__ __launch_bounds__(NTHREADS, 2)
void lstm2_uni_kernel(const float* __restrict__ feat,
                      const float* __restrict__ w_ih0,
                      const float* __restrict__ w_hh0,
                      const float* __restrict__ b_0,
                      const float* __restrict__ w_ih1,
                      const float* __restrict__ w_hh1,
                      const float* __restrict__ b_1,
                      const float* __restrict__ w_fc1,
                      const float* __restrict__ b_fc1,
                      const float* __restrict__ w_fc2,
                      const float* __restrict__ b_fc2,
                      float* __restrict__ out)
{
    __shared__ __align__(16) half_t smW[128 * W1K];          // 32 KB staging scratch
    __shared__ __align__(16) half_t Xh[2][BT * RS];          // 10.2 KB
    __shared__ __align__(16) half_t Xl[2][BT * RS];          // 10.2 KB  (total 53 KB)

    const int tid  = threadIdx.x;
    const int lane = tid & 63;
    const int wv   = tid >> 6;        // wave 0..3; wave wv owns M-tiles 4wv..4wv+3 (rows 64wv..64wv+63)
    const int quad = lane >> 4;
    const int col  = lane & 15;
    const int k0q  = quad * 8;
    const int b0   = blockIdx.x * BT;

    // Unit-interleaved rows: row 4j+q = gate q (i,f,g,o) of unit j; orig = q*50+j. Rows>=200 zero.
    auto w0val = [&](int r, int k) -> float {
        if (r >= 200) return 0.0f;
        int j = r >> 2, q = r & 3, orig = q * HID + j;
        if (k < IN0) return w_ih0[orig * IN0 + k];
        if (k < OFF_H0) return 0.0f;
        int u = k - OFF_H0;
        return (u < HID) ? w_hh0[orig * HID + u] : 0.0f;
    };
    auto w1val = [&](int r, int k) -> float {
        if (r >= 200) return 0.0f;
        int j = r >> 2, q = r & 3, orig = q * HID + j;
        if (k < 64) { return (k < HID) ? w_ih1[orig * HID + k] : 0.0f; }          // x h0
        int u = k - 64;
        return (u < HID) ? w_hh1[orig * HID + u] : 0.0f;                           // x h1
    };

    const int lrow = 64 * (wv & 1) + col;   // local row within 128-row staging half (+16*ti)
    half8 a0f[3][4], a1f[4][4];

    // ---- W0: two 128-row halves through scratch ----
    #pragma unroll 1
    for (int h = 0; h < 2; ++h) {
        for (int i = tid; i < 128 * W0K; i += NTHREADS) {
            int r = i / W0K, kk = i - r * W0K;
            smW[i] = (half_t)w0val(128 * h + r, kk);
        }
        __syncthreads();
        if ((wv >> 1) == h) {
            #pragma unroll
            for (int kt = 0; kt < 3; ++kt)
                #pragma unroll
                for (int ti = 0; ti < 4; ++ti)
                    a0f[kt][ti] = *(const half8*)(smW + (lrow + 16 * ti) * W0K + 32 * kt + k0q);
        }
        __syncthreads();
    }
    // ---- W1: two 128-row halves ----
    #pragma unroll 1
    for (int h = 0; h < 2; ++h) {
        for (int i = tid; i < 128 * W1K; i += NTHREADS) {
            int r = i >> 7, kk = i & 127;
            smW[i] = (half_t)w1val(128 * h + r, kk);
        }
        __syncthreads();
        if ((wv >> 1) == h) {
            #pragma unroll
            for (int kt = 0; kt < 4; ++kt)
                #pragma unroll
                for (int ti = 0; ti < 4; ++ti)
                    a1f[kt][ti] = *(const half8*)(smW + (lrow + 16 * ti) * W1K + 32 * kt + k0q);
        }
        __syncthreads();
    }
    // ---- Wf staging + X zero-init (disjoint) ----
    for (int i = tid; i < 32 * WFK; i += NTHREADS) {
        int r = i >> 6, kk = i & 63;
        smW[i] = (half_t)((r < 25 && kk < HID) ? w_fc1[r * HID + kk] : 0.0f);
    }
    for (int i = tid; i < BT * RS; i += NTHREADS) {
        Xh[0][i] = (half_t)0.0f; Xl[0][i] = (half_t)0.0f;
        Xh[1][i] = (half_t)0.0f; Xl[1][i] = (half_t)0.0f;
    }
    __syncthreads();   // staging+zeroing complete before reads/feature writes (round-3 lesson)

    const half8 hz = {0, 0, 0, 0, 0, 0, 0, 0};
    half8 wff[2][2];
    wff[0][0] = hz; wff[0][1] = hz; wff[1][0] = hz; wff[1][1] = hz;
    if (wv == 0) {
        #pragma unroll
        for (int kt = 0; kt < 2; ++kt)
            #pragma unroll
            for (int tf = 0; tf < 2; ++tf)
                wff[kt][tf] = *(const half8*)(smW + (16 * tf + col) * WFK + 32 * kt + k0q);
    }

    // ---- t=0 features ----
    const int xs = tid >> 4, xk = tid & 15;
    const size_t fbase = (size_t)(b0 + xs) * (TSTEPS * SDIM) + xk;
    hsplit(feat[fbase], &Xh[0][xs * RS + xk], &Xl[0][xs * RS + xk]);

    // ---- biases (u = 4*(4wv+ti)+quad; pad units get 0) ----
    floatx4 bias0[4], bias1[4];
    #pragma unroll
    for (int ti = 0; ti < 4; ++ti) {
        floatx4 z = {0.f, 0.f, 0.f, 0.f};
        bias0[ti] = z; bias1[ti] = z;
        int u = 4 * (4 * wv + ti) + quad;
        if (u < HID) {
            bias0[ti][0] = b_0[u];           bias0[ti][1] = b_0[HID + u];
            bias0[ti][2] = b_0[2 * HID + u]; bias0[ti][3] = b_0[3 * HID + u];
            bias1[ti][0] = b_1[u];           bias1[ti][1] = b_1[HID + u];
            bias1[ti][2] = b_1[2 * HID + u]; bias1[ti][3] = b_1[3 * HID + u];
        }
    }
    floatx4 w2r[2], bfr[2];
    { floatx4 z = {0.f, 0.f, 0.f, 0.f}; w2r[0] = z; w2r[1] = z; bfr[0] = z; bfr[1] = z; }
    float bf2 = 0.0f;
    if (wv == 0) {
        bf2 = b_fc2[0];
        #pragma unroll
        for (int tf = 0; tf < 2; ++tf)
            #pragma unroll
            for (int r5 = 0; r5 < 4; ++r5) {
                int r = 16 * tf + quad * 4 + r5;
                if (r < 25) { w2r[tf][r5] = w_fc2[r]; bfr[tf][r5] = b_fc1[r]; }
            }
    }

    float c0s[4] = {0.f, 0.f, 0.f, 0.f};
    float c1s[4] = {0.f, 0.f, 0.f, 0.f};
    // forwarded h0 fragments (= h0(t-1) in cur-buffer); zero at t=0
    half8 nb1h = hz, nb1l = hz, nb2h = hz, nb2l = hz;

    half_t* Xhc = Xh[0]; half_t* Xlc = Xl[0];
    half_t* Xhn = Xh[1]; half_t* Xln = Xl[1];
    __syncthreads();

    for (int t = 0; t < TSTEPS; ++t) {
        float fnext = (t + 1 < TSTEPS) ? feat[fbase + (size_t)(t + 1) * SDIM] : 0.0f;

        // ===== P1: layer-0 gates. kt0 from LDS; kt1,2 = forwarded h0 frags =====
        floatx4 acc[4];
        #pragma unroll
        for (int ti = 0; ti < 4; ++ti) acc[ti] = bias0[ti];
        {
            half8 bh = *(const half8*)(Xhc + col * RS + k0q);
            half8 bl = *(const half8*)(Xlc + col * RS + k0q);
            #pragma unroll
            for (int ti = 0; ti < 4; ++ti) {
                acc[ti] = MFMA16(a0f[0][ti], bh, acc[ti]);
                acc[ti] = MFMA16(a0f[0][ti], bl, acc[ti]);
            }
        }
        #pragma unroll
        for (int ti = 0; ti < 4; ++ti) {
            acc[ti] = MFMA16(a0f[1][ti], nb1h, acc[ti]);
            acc[ti] = MFMA16(a0f[1][ti], nb1l, acc[ti]);
            acc[ti] = MFMA16(a0f[2][ti], nb2h, acc[ti]);
            acc[ti] = MFMA16(a0f[2][ti], nb2l, acc[ti]);
        }

        // ===== P2: layer-0 cell update (regs) -> h0 into NXT buffer (single store site) =====
        #pragma unroll
        for (int ti = 0; ti < 4; ++ti) {
            int u = 4 * (4 * wv + ti) + quad;
            float i_ = sig_u(acc[ti][0]);
            float f_ = sig_u(acc[ti][1]);
            float g_ = tanh_u(acc[ti][2]);
            float o_ = sig_u(acc[ti][3]);
            float c  = f_ * c0s[ti] + i_ * g_;
            c0s[ti]  = c;
            float hv = o_ * tanh_u(c);
            half_t hh, hl; hsplit(hv, &hh, &hl);
            Xhn[col * RS + OFF_H0 + u] = hh;
            Xln[col * RS + OFF_H0 + u] = hl;
        }
        __syncthreads();   // B_a: h0(t) visible

        // ===== P3: layer-1 gates. kt0,1 = h0(t) from NXT (loads double as next-P1 forwards);
        //                          kt2,3 = h1(t-1) from CUR =====
        floatx4 acc1[4];
        #pragma unroll
        for (int ti = 0; ti < 4; ++ti) acc1[ti] = bias1[ti];
        nb1h = *(const half8*)(Xhn + col * RS + OFF_H0 + k0q);
        nb1l = *(const half8*)(Xln + col * RS + OFF_H0 + k0q);
        #pragma unroll
        for (int ti = 0; ti < 4; ++ti) {
            acc1[ti] = MFMA16(a1f[0][ti], nb1h, acc1[ti]);
            acc1[ti] = MFMA16(a1f[0][ti], nb1l, acc1[ti]);
        }
        nb2h = *(const half8*)(Xhn + col * RS + OFF_H0 + 32 + k0q);
        nb2l = *(const half8*)(Xln + col * RS + OFF_H0 + 32 + k0q);
        #pragma unroll
        for (int ti = 0; ti < 4; ++ti) {
            acc1[ti] = MFMA16(a1f[1][ti], nb2h, acc1[ti]);
            acc1[ti] = MFMA16(a1f[1][ti], nb2l, acc1[ti]);
        }
        #pragma unroll
        for (int kt = 2; kt < 4; ++kt) {
            half8 bh = *(const half8*)(Xhc + col * RS + OFF_H1 + 32 * (kt - 2) + k0q);
            half8 bl = *(const half8*)(Xlc + col * RS + OFF_H1 + 32 * (kt - 2) + k0q);
            #pragma unroll
            for (int ti = 0; ti < 4; ++ti) {
                acc1[ti] = MFMA16(a1f[kt][ti], bh, acc1[ti]);
                acc1[ti] = MFMA16(a1f[kt][ti], bl, acc1[ti]);
            }
        }

        // ===== P4: layer-1 cell update -> h1 into NXT =====
        #pragma unroll
        for (int ti = 0; ti < 4; ++ti) {
            int u = 4 * (4 * wv + ti) + quad;
            float i_ = sig_u(acc1[ti][0]);
            float f_ = sig_u(acc1[ti][1]);
            float g_ = tanh_u(acc1[ti][2]);
            float o_ = sig_u(acc1[ti][3]);
            float c  = f_ * c1s[ti] + i_ * g_;
            c1s[ti]  = c;
            float hv = o_ * tanh_u(c);
            half_t hh, hl; hsplit(hv, &hh, &hl);
            Xhn[col * RS + OFF_H1 + u] = hh;
            Xln[col * RS + OFF_H1 + u] = hl;
        }
        __syncthreads();   // B_b: h1(t) visible

        // ===== P5: FC head (wave 0) + feature staging (all waves) =====
        if (wv == 0) {
            floatx4 accf[2]; accf[0] = bfr[0]; accf[1] = bfr[1];
            #pragma unroll
            for (int kt = 0; kt < 2; ++kt) {
                half8 bh = *(const half8*)(Xhn + col * RS + OFF_H1 + 32 * kt + k0q);
                half8 bl = *(const half8*)(Xln + col * RS + OFF_H1 + 32 * kt + k0q);
                #pragma unroll
                for (int tf = 0; tf < 2; ++tf) {
                    accf[tf] = MFMA16(wff[kt][tf], bh, accf[tf]);
                    accf[tf] = MFMA16(wff[kt][tf], bl, accf[tf]);
                }
            }
            float p = 0.0f;
            #pragma unroll
            for (int tf = 0; tf < 2; ++tf)
                #pragma unroll
                for (int r5 = 0; r5 < 4; ++r5)
                    p += w2r[tf][r5] * fmaxf(accf[tf][r5], 0.0f);
            p += __shfl_xor(p, 16);
            p += __shfl_xor(p, 32);
            float d = p + bf2;
            if (lane < 16) {
                out[(size_t)(b0 + lane) * TSTEPS + t] = d;
                hsplit(d, &Xhn[lane * RS + 16], &Xln[lane * RS + 16]);   // prev_delta
            }
        }
        if (t + 1 < TSTEPS)
            hsplit(fnext, &Xhn[xs * RS + xk], &Xln[xs * RS + xk]);
        __syncthreads();   // B_c: NXT fully staged

        // swap buffers
        half_t* tp;
        tp = Xhc; Xhc = Xhn; Xhn = tp;
        tp = Xlc; Xlc = Xln; Xln = tp;
    }
}

extern "C" void kernel_launch(void* const* d_in, const int* in_sizes, int n_in,
                              void* d_out, int out_size, void* d_ws, size_t ws_size,
                              hipStream_t stream) {
    const float* feat  = (const float*)d_in[0];
    const float* w_ih0 = (const float*)d_in[1];
    const float* w_hh0 = (const float*)d_in[2];
    const float* b_0   = (const float*)d_in[3];
    const float* w_ih1 = (const float*)d_in[4];
    const float* w_hh1 = (const float*)d_in[5];
    const float* b_1   = (const float*)d_in[6];
    const float* w_fc1 = (const float*)d_in[7];
    const float* b_fc1 = (const float*)d_in[8];
    const float* w_fc2 = (const float*)d_in[9];
    const float* b_fc2 = (const float*)d_in[10];
    float* out = (float*)d_out;

    dim3 grid(BATCH / BT);   // 512 blocks, 53 KB LDS -> 2 blocks/CU, all resident
    dim3 block(NTHREADS);
    hipLaunchKernelGGL(lstm2_uni_kernel, grid, block, 0, stream,
                       feat, w_ih0, w_hh0, b_0, w_ih1, w_hh1, b_1,
                       w_fc1, b_fc1, w_fc2, b_fc2, out);
}

// Round 8
// 478.040 us; speedup vs baseline: 1.0141x; 1.0141x over previous
//
#include <hip/hip_runtime.h>
#include <math.h>

#define BATCH    8192
#define TSTEPS   128
#define SDIM     16
#define HID      50
#define IN0      17
#define BT       16     // samples per block = MFMA N
#define NTHREADS 512    // 8 waves; 2 blocks/CU target (4 waves/SIMD)

// X row layout (f16 elems), double-buffered, stride RS:
//  k 0..15: features   k16: delta (unused in LDS - reg-injected)  k17: one (reg-injected)
//  k18..31: zero       k32..95: h0 (u0..49 real, u50=const-1 for b_1, rest 0)
//  k96..159: h1 (u0..49 real, u50=const-1 for b_fc1, rest 0)
#define RS      160
#define OFF_H0  32
#define OFF_H1  96
#define W0K     96      // cols: [w_ih0(17) | b_0(@17) | 0..31 | w_hh0(50)+0pad]
#define W1K     128     // cols: [w_ih1(50) | b_1(@50) | 0..63 | w_hh1(50) | 0(@50!) +pad]
#define WFK     64      // cols: [w_fc1(50) | b_fc1(@50) | 0 pad]

typedef _Float16 half_t;
typedef __attribute__((ext_vector_type(8))) _Float16 half8;
typedef __attribute__((ext_vector_type(4))) float    floatx4;

#define MFMA16(a, b, c) __builtin_amdgcn_mfma_f32_16x16x32_f16((a), (b), (c), 0, 0, 0)

__device__ __forceinline__ float sig_u(float x) {
    float e = __expf(-x);
    return __builtin_amdgcn_rcpf(1.0f + e);
}
__device__ __forceinline__ float tanh_u(float x) {
    float e = __expf(-2.0f * x);
    return fmaf(2.0f, __builtin_amdgcn_rcpf(1.0f + e), -1.0f);
}
__device__ __forceinline__ void hsplit(float v, half_t* hp, half_t* lp) {
    half_t h = (half_t)v;
    *hp = h;
    *lp = (half_t)(v - (float)h);
}

__global__ __launch_bounds__(NTHREADS, 4)   // 4 waves/EU -> VGPR cap 128 -> 2 blocks/CU
void lstm2_w8_kernel(const float* __restrict__ feat,
                     const float* __restrict__ w_ih0,
                     const float* __restrict__ w_hh0,
                     const float* __restrict__ b_0,
                     const float* __restrict__ w_ih1,
                     const float* __restrict__ w_hh1,
                     const float* __restrict__ b_1,
                     const float* __restrict__ w_fc1,
                     const float* __restrict__ b_fc1,
                     const float* __restrict__ w_fc2,
                     const float* __restrict__ b_fc2,
                     float* __restrict__ out)
{
    __shared__ __align__(16) half_t smW[64 * W1K];               // 16 KB chunk scratch
    __shared__ __align__(16) half_t Xh[2][BT * RS];              // 10 KB
    __shared__ __align__(16) half_t Xl[2][BT * RS];              // 10 KB   (37 KB total)

    const int tid  = threadIdx.x;
    const int lane = tid & 63;
    const int wv   = tid >> 6;          // 0..7; wave w owns M-tiles {2w, 2w+1} (rows 32w..32w+31)
    const int quad = lane >> 4;
    const int col  = lane & 15;
    const int k0q  = quad * 8;
    const int b0   = blockIdx.x * BT;
    const int tcnt = (wv < 6) ? 2 : (wv == 6 ? 1 : 0);   // real-tile count (13 tiles total)

    // Unit-interleaved rows: row 4j+q = gate q (i,f,g,o) of unit j; orig = q*50+j. Rows>=200 zero.
    auto w0val = [&](int r, int k) -> float {
        if (r >= 200) return 0.0f;
        int j = r >> 2, q = r & 3, orig = q * HID + j;
        if (k < IN0)  return w_ih0[orig * IN0 + k];
        if (k == IN0) return b_0[orig];                       // bias via x const-1 @k17
        if (k < OFF_H0) return 0.0f;
        int u = k - OFF_H0;
        return (u < HID) ? w_hh0[orig * HID + u] : 0.0f;      // h0-pad cols (incl u50) zero
    };
    auto w1val = [&](int r, int k) -> float {
        if (r >= 200) return 0.0f;
        int j = r >> 2, q = r & 3, orig = q * HID + j;
        if (k < 64) {
            if (k < HID)  return w_ih1[orig * HID + k];       // x h0
            if (k == HID) return b_1[orig];                   // bias via h0 const-1 slot
            return 0.0f;
        }
        int u = k - 64;                                       // x h1; u50 stays 0 (protects FC const-1)
        return (u < HID) ? w_hh1[orig * HID + u] : 0.0f;
    };

    // ---- stage weights through 16KB scratch, 64-row chunks; waves {2c,2c+1} grab frags of chunk c
    half8 a0f[3][2], a1f[4][2];
    const int lbase = 32 * (wv & 1) + col;
    #pragma unroll 1
    for (int c = 0; c < 4; ++c) {
        for (int i = tid; i < 64 * W0K; i += NTHREADS) {
            int r = i / W0K, k = i - r * W0K;
            smW[i] = (half_t)w0val(64 * c + r, k);
        }
        __syncthreads();
        if ((wv >> 1) == c) {
            #pragma unroll
            for (int kt = 0; kt < 3; ++kt)
                #pragma unroll
                for (int ti = 0; ti < 2; ++ti)
                    a0f[kt][ti] = *(const half8*)(smW + (lbase + 16 * ti) * W0K + 32 * kt + k0q);
        }
        __syncthreads();
    }
    #pragma unroll 1
    for (int c = 0; c < 4; ++c) {
        for (int i = tid; i < 64 * W1K; i += NTHREADS) {
            int r = i >> 7, k = i & 127;
            smW[i] = (half_t)w1val(64 * c + r, k);
        }
        __syncthreads();
        if ((wv >> 1) == c) {
            #pragma unroll
            for (int kt = 0; kt < 4; ++kt)
                #pragma unroll
                for (int ti = 0; ti < 2; ++ti)
                    a1f[kt][ti] = *(const half8*)(smW + (lbase + 16 * ti) * W1K + 32 * kt + k0q);
        }
        __syncthreads();
    }
    // Wf (32x64): rows 0..24 real, col 50 = b_fc1
    for (int i = tid; i < 32 * WFK; i += NTHREADS) {
        int r = i >> 6, k = i & 63;
        float v = 0.0f;
        if (r < 25) { if (k < HID) v = w_fc1[r * HID + k]; else if (k == HID) v = b_fc1[r]; }
        smW[i] = (half_t)v;
    }
    __syncthreads();
    half8 wff[2][2];
    #pragma unroll
    for (int kt = 0; kt < 2; ++kt)
        #pragma unroll
        for (int tf = 0; tf < 2; ++tf)
            wff[kt][tf] = *(const half8*)(smW + (16 * tf + col) * WFK + 32 * kt + k0q);

    // ---- X buffers: zero, then const-1 slots + t=0 features (barrier between: round-3 lesson)
    for (int i = tid; i < BT * RS; i += NTHREADS) {
        Xh[0][i] = (half_t)0.0f; Xl[0][i] = (half_t)0.0f;
        Xh[1][i] = (half_t)0.0f; Xl[1][i] = (half_t)0.0f;
    }
    __syncthreads();
    if (tid < BT) {   // const-1 slots (hi=1, lo=0) in BOTH buffers; never overwritten (u<50 store guard)
        Xh[0][tid * RS + OFF_H0 + HID] = (half_t)1.0f;
        Xh[1][tid * RS + OFF_H0 + HID] = (half_t)1.0f;
        Xh[0][tid * RS + OFF_H1 + HID] = (half_t)1.0f;
        Xh[1][tid * RS + OFF_H1 + HID] = (half_t)1.0f;
    }
    const bool stager = (tid < BT * SDIM);                // 256 feature loaders
    const int  xs = tid >> 4, xk = tid & 15;
    const size_t fbase = (size_t)(b0 + (stager ? xs : 0)) * (TSTEPS * SDIM) + xk;
    if (stager) hsplit(feat[fbase], &Xh[0][xs * RS + xk], &Xl[0][xs * RS + xk]);

    // ---- per-lane FC output consts (all waves: FC is computed redundantly everywhere)
    floatx4 w2r[2];
    { floatx4 z = {0.f, 0.f, 0.f, 0.f}; w2r[0] = z; w2r[1] = z; }
    #pragma unroll
    for (int tf = 0; tf < 2; ++tf)
        #pragma unroll
        for (int r5 = 0; r5 < 4; ++r5) {
            int r = 16 * tf + 4 * quad + r5;
            if (r < 25) w2r[tf][r5] = w_fc2[r];
        }
    const float bf2 = b_fc2[0];

    const half8   hz = {0, 0, 0, 0, 0, 0, 0, 0};
    const floatx4 fz = {0.f, 0.f, 0.f, 0.f};
    float c0s[2] = {0.f, 0.f};
    float c1s[2] = {0.f, 0.f};
    half_t dh = (half_t)0.0f, dl = (half_t)0.0f;   // prev_delta hi/lo (reg-resident)

    half_t* Xhc = Xh[0]; half_t* Xlc = Xl[0];
    half_t* Xhn = Xh[1]; half_t* Xln = Xl[1];
    __syncthreads();

    for (int t = 0; t < TSTEPS; ++t) {
        float fnext = 0.0f;
        if (stager && (t + 1 < TSTEPS)) fnext = feat[fbase + (size_t)(t + 1) * SDIM];

        // ===== P1: layer-0 gates (bias via const-1 col; acc init zero) =====
        floatx4 acc[2]; acc[0] = fz; acc[1] = fz;
        if (tcnt > 0) {
            // kt0: x region. quad0/1: features from LDS; quad2: [delta, 1, 0...] from regs; quad3: 0
            half8 bh0, bl0;
            if (quad < 2) {
                bh0 = *(const half8*)(Xhc + col * RS + k0q);
                bl0 = *(const half8*)(Xlc + col * RS + k0q);
            } else {
                bh0 = hz; bl0 = hz;
                if (quad == 2) { bh0[0] = dh; bh0[1] = (half_t)1.0f; bl0[0] = dl; }
            }
            #pragma unroll
            for (int ti = 0; ti < 2; ++ti)
                if (ti < tcnt) {
                    acc[ti] = MFMA16(a0f[0][ti], bh0, acc[ti]);
                    acc[ti] = MFMA16(a0f[0][ti], bl0, acc[ti]);
                }
            #pragma unroll
            for (int kt = 1; kt < 3; ++kt) {
                half8 bh = *(const half8*)(Xhc + col * RS + OFF_H0 + 32 * (kt - 1) + k0q);
                half8 bl = *(const half8*)(Xlc + col * RS + OFF_H0 + 32 * (kt - 1) + k0q);
                #pragma unroll
                for (int ti = 0; ti < 2; ++ti)
                    if (ti < tcnt) {
                        acc[ti] = MFMA16(a0f[kt][ti], bh, acc[ti]);
                        acc[ti] = MFMA16(a0f[kt][ti], bl, acc[ti]);
                    }
            }
        }

        // ===== P2: layer-0 cell update -> h0(t) into NXT =====
        #pragma unroll
        for (int ti = 0; ti < 2; ++ti)
            if (ti < tcnt) {
                int u = 8 * wv + 4 * ti + quad;
                float i_ = sig_u(acc[ti][0]);
                float f_ = sig_u(acc[ti][1]);
                float g_ = tanh_u(acc[ti][2]);
                float o_ = sig_u(acc[ti][3]);
                float c  = f_ * c0s[ti] + i_ * g_;
                c0s[ti]  = c;
                float hv = o_ * tanh_u(c);
                if (u < HID) {
                    half_t hh, hl; hsplit(hv, &hh, &hl);
                    Xhn[col * RS + OFF_H0 + u] = hh;
                    Xln[col * RS + OFF_H0 + u] = hl;
                }
            }
        __syncthreads();   // B_a: h0(t) visible

        // feature staging for t+1 into NXT (x region; disjoint from all reads below)
        if (stager && (t + 1 < TSTEPS))
            hsplit(fnext, &Xhn[xs * RS + xk], &Xln[xs * RS + xk]);

        // ===== P3: layer-1 gates: kt0,1 = h0(t) (NXT), kt2,3 = h1(t-1) (CUR) =====
        floatx4 acc1[2]; acc1[0] = fz; acc1[1] = fz;
        if (tcnt > 0) {
            #pragma unroll
            for (int kt = 0; kt < 2; ++kt) {
                half8 bh = *(const half8*)(Xhn + col * RS + OFF_H0 + 32 * kt + k0q);
                half8 bl = *(const half8*)(Xln + col * RS + OFF_H0 + 32 * kt + k0q);
                #pragma unroll
                for (int ti = 0; ti < 2; ++ti)
                    if (ti < tcnt) {
                        acc1[ti] = MFMA16(a1f[kt][ti], bh, acc1[ti]);
                        acc1[ti] = MFMA16(a1f[kt][ti], bl, acc1[ti]);
                    }
            }
            #pragma unroll
            for (int kt = 2; kt < 4; ++kt) {
                half8 bh = *(const half8*)(Xhc + col * RS + OFF_H1 + 32 * (kt - 2) + k0q);
                half8 bl = *(const half8*)(Xlc + col * RS + OFF_H1 + 32 * (kt - 2) + k0q);
                #pragma unroll
                for (int ti = 0; ti < 2; ++ti)
                    if (ti < tcnt) {
                        acc1[ti] = MFMA16(a1f[kt][ti], bh, acc1[ti]);
                        acc1[ti] = MFMA16(a1f[kt][ti], bl, acc1[ti]);
                    }
            }
        }

        // ===== P4: layer-1 cell update -> h1(t) into NXT =====
        #pragma unroll
        for (int ti = 0; ti < 2; ++ti)
            if (ti < tcnt) {
                int u = 8 * wv + 4 * ti + quad;
                float i_ = sig_u(acc1[ti][0]);
                float f_ = sig_u(acc1[ti][1]);
                float g_ = tanh_u(acc1[ti][2]);
                float o_ = sig_u(acc1[ti][3]);
                float c  = f_ * c1s[ti] + i_ * g_;
                c1s[ti]  = c;
                float hv = o_ * tanh_u(c);
                if (u < HID) {
                    half_t hh, hl; hsplit(hv, &hh, &hl);
                    Xhn[col * RS + OFF_H1 + u] = hh;
                    Xln[col * RS + OFF_H1 + u] = hl;
                }
            }
        __syncthreads();   // B_b: h1(t) + features(t+1) visible

        // ===== P5: FC head, computed redundantly by ALL waves (b_fc1 via const-1 col 50) =====
        floatx4 accf[2]; accf[0] = fz; accf[1] = fz;
        #pragma unroll
        for (int kt = 0; kt < 2; ++kt) {
            half8 bh = *(const half8*)(Xhn + col * RS + OFF_H1 + 32 * kt + k0q);
            half8 bl = *(const half8*)(Xln + col * RS + OFF_H1 + 32 * kt + k0q);
            #pragma unroll
            for (int tf = 0; tf < 2; ++tf) {
                accf[tf] = MFMA16(wff[kt][tf], bh, accf[tf]);
                accf[tf] = MFMA16(wff[kt][tf], bl, accf[tf]);
            }
        }
        float p = 0.0f;
        #pragma unroll
        for (int tf = 0; tf < 2; ++tf)
            #pragma unroll
            for (int r5 = 0; r5 < 4; ++r5)
                p += w2r[tf][r5] * fmaxf(accf[tf][r5], 0.0f);
        p += __shfl_xor(p, 16);
        p += __shfl_xor(p, 32);          // now every lane holds d for its col
        float d = p + bf2;
        if (wv == 0 && lane < 16)
            out[(size_t)(b0 + lane) * TSTEPS + t] = d;
        hsplit(d, &dh, &dl);             // reg-resident prev_delta for next P1

        // swap buffers (no barrier needed: next P1/P2 touch only regions
        // whose last cross-wave access is already separated by B_a/B_b)
        half_t* tp;
        tp = Xhc; Xhc = Xhn; Xhn = tp;
        tp = Xlc; Xlc = Xln; Xln = tp;
    }
}

extern "C" void kernel_launch(void* const* d_in, const int* in_sizes, int n_in,
                              void* d_out, int out_size, void* d_ws, size_t ws_size,
                              hipStream_t stream) {
    const float* feat  = (const float*)d_in[0];
    const float* w_ih0 = (const float*)d_in[1];
    const float* w_hh0 = (const float*)d_in[2];
    const float* b_0   = (const float*)d_in[3];
    const float* w_ih1 = (const float*)d_in[4];
    const float* w_hh1 = (const float*)d_in[5];
    const float* b_1   = (const float*)d_in[6];
    const float* w_fc1 = (const float*)d_in[7];
    const float* b_fc1 = (const float*)d_in[8];
    const float* w_fc2 = (const float*)d_in[9];
    const float* b_fc2 = (const float*)d_in[10];
    float* out = (float*)d_out;

    dim3 grid(BATCH / BT);   // 512 blocks x 512 threads; 37 KB LDS, <=128 VGPR -> 2 blocks/CU
    dim3 block(NTHREADS);
    hipLaunchKernelGGL(lstm2_w8_kernel, grid, block, 0, stream,
                       feat, w_ih0, w_hh0, b_0, w_ih1, w_hh1, b_1,
                       w_fc1, b_fc1, w_fc2, b_fc2, out);
}